// Round 1
// baseline (2126.322 us; speedup 1.0000x reference)
//
#include <hip/hip_runtime.h>

// Problem dims (fixed by reference)
#define B_DIM 32
#define T_DIM 1024
#define I_DIM 4
#define H_DIM 2048
#define O_DIM 2
#define R_DIM 2
#define S_DIM 2
#define G_DIM 8

#define NOISE_STD 0.05f
#define ALPHA 0.2f
#define INV_H (1.0f / (float)H_DIM)

#define NTHREADS 512
#define EPT 4                    // h-elements per thread (NTHREADS*EPT == H_DIM)
#define NWAVES (NTHREADS / 64)
#define PF_DEPTH 4               // noise prefetch ring depth

// LDS small-weight layout offsets (floats)
#define WIW 0    // (I,S,G) = 64
#define MW  64   // (R,S,G) = 32
#define NW  96   // (R,S,G) = 32
#define WOW 128  // (O,S,G) = 32
#define WIB 160  // (I,S)   = 8
#define MB  168  // (R,S)   = 4
#define NB  172  // (R,S)   = 4
#define H0W 176  // (S,G)   = 16
#define WTOT 192

__device__ __forceinline__ float f4get(const float4 v, int e) {
    return e == 0 ? v.x : e == 1 ? v.y : e == 2 ? v.z : v.w;
}
__device__ __forceinline__ void f4set(float4& v, int e, float x) {
    if (e == 0) v.x = x; else if (e == 1) v.y = x; else if (e == 2) v.z = x; else v.w = x;
}

__device__ __forceinline__ float fast_tanh(float x) {
    // tanh(x) = 1 - 2/(exp(2x)+1); saturates correctly for |x| large
    float e2 = __expf(2.0f * x);
    return 1.0f - 2.0f / (e2 + 1.0f);
}

__global__ __launch_bounds__(NTHREADS) void rnn_kernel(
    const float* __restrict__ input,   // (B,T,I)
    const float* __restrict__ noise,   // (B,T,H)
    const float* __restrict__ gb,      // (G,H)
    const float* __restrict__ sup,     // (S,H)
    const float* __restrict__ wi_w,    // (I,S,G)
    const float* __restrict__ m_w,     // (R,S,G)
    const float* __restrict__ n_w,     // (R,S,G)
    const float* __restrict__ wo_w,    // (O,S,G)
    const float* __restrict__ wi_b,    // (I,S)
    const float* __restrict__ m_b,     // (R,S)
    const float* __restrict__ n_b,     // (R,S)
    const float* __restrict__ h0_w,    // (S,G)
    float* __restrict__ out)           // (B,T,O) then (B,T,H), flat
{
    const int b    = blockIdx.x;
    const int tid  = threadIdx.x;
    const int wave = tid >> 6;
    const int lane = tid & 63;

    __shared__ float  s_input[T_DIM * I_DIM];  // 16 KB: input[b] staged
    __shared__ float2 s_out[T_DIM];            // 8 KB: per-step (o0,o1)
    __shared__ float4 s_part[2][NWAVES];       // double-buffered wave partials
    __shared__ float  s_w[WTOT];               // small weights

    // ---- stage input[b] and small weights into LDS ----
    {
        const float4* inp4 = (const float4*)(input + (size_t)b * (T_DIM * I_DIM));
        float4* sIn4 = (float4*)s_input;
        #pragma unroll
        for (int k = tid; k < T_DIM * I_DIM / 4; k += NTHREADS) sIn4[k] = inp4[k];

        if (tid < 64)       s_w[tid] = wi_w[tid];
        else if (tid < 96)  s_w[tid] = m_w[tid - 64];
        else if (tid < 128) s_w[tid] = n_w[tid - 96];
        else if (tid < 160) s_w[tid] = wo_w[tid - 128];
        else if (tid < 168) s_w[tid] = wi_b[tid - 160];
        else if (tid < 172) s_w[tid] = m_b[tid - 168];
        else if (tid < 176) s_w[tid] = n_b[tid - 172];
        else if (tid < 192) s_w[tid] = h0_w[tid - 176];
    }
    __syncthreads();

    // ---- build per-thread proxy weights for my EPT h-indices ----
    const int h_base = tid * EPT;

    float4 gbv[G_DIM];
    #pragma unroll
    for (int g = 0; g < G_DIM; ++g)
        gbv[g] = *(const float4*)(gb + (size_t)g * H_DIM + h_base);
    float4 supv[S_DIM];
    #pragma unroll
    for (int s = 0; s < S_DIM; ++s)
        supv[s] = *(const float4*)(sup + (size_t)s * H_DIM + h_base);

    float wiP[EPT][I_DIM], mP[EPT][R_DIM], nP[EPT][R_DIM], woP[EPT][O_DIM];
    float h_reg[EPT], g_reg[EPT];

    #pragma unroll
    for (int e = 0; e < EPT; ++e) {
        float gcol[G_DIM];
        #pragma unroll
        for (int g = 0; g < G_DIM; ++g) gcol[g] = f4get(gbv[g], e);

        #pragma unroll
        for (int i = 0; i < I_DIM; ++i) wiP[e][i] = 0.0f;
        #pragma unroll
        for (int r = 0; r < R_DIM; ++r) { mP[e][r] = 0.0f; nP[e][r] = 0.0f; }
        #pragma unroll
        for (int o = 0; o < O_DIM; ++o) woP[e][o] = 0.0f;
        float h0v = 0.0f;

        #pragma unroll
        for (int s = 0; s < S_DIM; ++s) {
            float sv = f4get(supv[s], e);
            #pragma unroll
            for (int i = 0; i < I_DIM; ++i) {
                float d = 0.0f;
                #pragma unroll
                for (int g = 0; g < G_DIM; ++g)
                    d = fmaf(s_w[WIW + (i * S_DIM + s) * G_DIM + g], gcol[g], d);
                wiP[e][i] = fmaf(sv, d + s_w[WIB + i * S_DIM + s], wiP[e][i]);
            }
            #pragma unroll
            for (int r = 0; r < R_DIM; ++r) {
                float dm = 0.0f, dn = 0.0f;
                #pragma unroll
                for (int g = 0; g < G_DIM; ++g) {
                    dm = fmaf(s_w[MW + (r * S_DIM + s) * G_DIM + g], gcol[g], dm);
                    dn = fmaf(s_w[NW + (r * S_DIM + s) * G_DIM + g], gcol[g], dn);
                }
                mP[e][r] = fmaf(sv, dm + s_w[MB + r * S_DIM + s], mP[e][r]);
                nP[e][r] = fmaf(sv, dn + s_w[NB + r * S_DIM + s], nP[e][r]);
            }
            #pragma unroll
            for (int o = 0; o < O_DIM; ++o) {
                float d = 0.0f;
                #pragma unroll
                for (int g = 0; g < G_DIM; ++g)
                    d = fmaf(s_w[WOW + (o * S_DIM + s) * G_DIM + g], gcol[g], d);
                woP[e][o] = fmaf(sv, d, woP[e][o]);
            }
            {
                float d = 0.0f;
                #pragma unroll
                for (int g = 0; g < G_DIM; ++g)
                    d = fmaf(s_w[H0W + s * G_DIM + g], gcol[g], d);
                h0v = fmaf(sv, d, h0v);
            }
        }
        h_reg[e] = h0v;                 // h_init = h0 (broadcast over batch)
        g_reg[e] = fast_tanh(h0v);      // r for step 0
    }

    // ---- pointers and noise prefetch ring ----
    const int strideF4 = H_DIM / 4;
    const float4* noi4 = (const float4*)(noise + (size_t)b * T_DIM * H_DIM + h_base);
    float4* trajp = (float4*)(out + (size_t)B_DIM * T_DIM * O_DIM
                                  + (size_t)b * T_DIM * H_DIM + h_base);

    float4 ring0 = noi4[(size_t)0 * strideF4];
    float4 ring1 = noi4[(size_t)1 * strideF4];
    float4 ring2 = noi4[(size_t)2 * strideF4];
    float4 ring3 = noi4[(size_t)3 * strideF4];

    // ---- main scan ----
    for (int t = 0; t < T_DIM; ++t) {
        const int buf = t & 1;

        // partials: kappa (g.n) and out_{t-1} (g.wo) from the SAME g
        float p0 = 0.f, p1 = 0.f, p2 = 0.f, p3 = 0.f;
        #pragma unroll
        for (int e = 0; e < EPT; ++e) {
            float g = g_reg[e];
            p0 = fmaf(g, nP[e][0], p0);
            p1 = fmaf(g, nP[e][1], p1);
            p2 = fmaf(g, woP[e][0], p2);
            p3 = fmaf(g, woP[e][1], p3);
        }
        #pragma unroll
        for (int off = 32; off > 0; off >>= 1) {
            p0 += __shfl_xor(p0, off, 64);
            p1 += __shfl_xor(p1, off, 64);
            p2 += __shfl_xor(p2, off, 64);
            p3 += __shfl_xor(p3, off, 64);
        }
        if (lane == 0) s_part[buf][wave] = make_float4(p0, p1, p2, p3);
        __syncthreads();

        float4 tot = s_part[buf][0];
        #pragma unroll
        for (int w = 1; w < NWAVES; ++w) {
            float4 q = s_part[buf][w];
            tot.x += q.x; tot.y += q.y; tot.z += q.z; tot.w += q.w;
        }
        if (t > 0 && tid == 0)
            s_out[t - 1] = make_float2(tot.z * INV_H, tot.w * INV_H);

        const float k0 = tot.x * INV_H;   // fold 1/H of rec into kappa
        const float k1 = tot.y * INV_H;

        // noise for this step from the ring; refill for t+PF_DEPTH
        float4 nz = ring0;
        ring0 = ring1; ring1 = ring2; ring2 = ring3;
        {
            int tp = t + PF_DEPTH; if (tp > T_DIM - 1) tp = T_DIM - 1;
            ring3 = noi4[(size_t)tp * strideF4];
        }

        const float4 uin = *(const float4*)(s_input + t * I_DIM);  // input[b,t,:]

        float4 hout;
        #pragma unroll
        for (int e = 0; e < EPT; ++e) {
            float u = uin.x * wiP[e][0];
            u = fmaf(uin.y, wiP[e][1], u);
            u = fmaf(uin.z, wiP[e][2], u);
            u = fmaf(uin.w, wiP[e][3], u);
            float rec = k0 * mP[e][0];
            rec = fmaf(k1, mP[e][1], rec);
            float h = h_reg[e];
            h = h + NOISE_STD * f4get(nz, e) + ALPHA * (rec + u - h);
            h_reg[e] = h;
            g_reg[e] = fast_tanh(h);
            f4set(hout, e, h);
        }
        *trajp = hout;          // trajectories[b,t,:]
        trajp += strideF4;
    }

    // ---- final out[T-1] reduction ----
    {
        float p2 = 0.f, p3 = 0.f;
        #pragma unroll
        for (int e = 0; e < EPT; ++e) {
            p2 = fmaf(g_reg[e], woP[e][0], p2);
            p3 = fmaf(g_reg[e], woP[e][1], p3);
        }
        #pragma unroll
        for (int off = 32; off > 0; off >>= 1) {
            p2 += __shfl_xor(p2, off, 64);
            p3 += __shfl_xor(p3, off, 64);
        }
        if (lane == 0) s_part[0][wave] = make_float4(p2, p3, 0.f, 0.f);
        __syncthreads();
        if (tid == 0) {
            float a = 0.f, c = 0.f;
            #pragma unroll
            for (int w = 0; w < NWAVES; ++w) { a += s_part[0][w].x; c += s_part[0][w].y; }
            s_out[T_DIM - 1] = make_float2(a * INV_H, c * INV_H);
        }
        __syncthreads();
    }

    // ---- flush output (B,T,O) block for this b: 2048 floats, coalesced ----
    {
        float4* outg = (float4*)(out + (size_t)b * T_DIM * O_DIM);
        const float4* outl = (const float4*)s_out;
        outg[tid] = outl[tid];   // 512 threads * 16B = 8KB
    }
}

extern "C" void kernel_launch(void* const* d_in, const int* in_sizes, int n_in,
                              void* d_out, int out_size, void* d_ws, size_t ws_size,
                              hipStream_t stream) {
    rnn_kernel<<<B_DIM, NTHREADS, 0, stream>>>(
        (const float*)d_in[0],  // input
        (const float*)d_in[1],  // noise
        (const float*)d_in[2],  // gaussian_basis
        (const float*)d_in[3],  // supports
        (const float*)d_in[4],  // wi_weights
        (const float*)d_in[5],  // m_weights
        (const float*)d_in[6],  // n_weights
        (const float*)d_in[7],  // wo_weights
        (const float*)d_in[8],  // wi_biases
        (const float*)d_in[9],  // m_biases
        (const float*)d_in[10], // n_biases
        (const float*)d_in[11], // h0_weights
        (float*)d_out);
}

// Round 2
// 1019.341 us; speedup vs baseline: 2.0860x; 2.0860x over previous
//
#include <hip/hip_runtime.h>

// Problem dims (fixed by reference)
#define B_DIM 32
#define T_DIM 1024
#define I_DIM 4
#define H_DIM 2048
#define O_DIM 2
#define R_DIM 2
#define S_DIM 2
#define G_DIM 8

#define NOISE_STD 0.05f
#define ALPHA 0.2f
#define INV_H (1.0f / (float)H_DIM)

#define NTHREADS 256
#define NWAVES (NTHREADS / 64)   // 4
#define EPT 8                    // h-elements per thread (2 float4 chunks)
#define PF_DEPTH 4               // noise prefetch ring depth (steps)

// LDS small-weight layout offsets (floats)
#define WIW 0    // (I,S,G) = 64
#define MW  64   // (R,S,G) = 32
#define NW  96   // (R,S,G) = 32
#define WOW 128  // (O,S,G) = 32
#define WIB 160  // (I,S)   = 8
#define MB  168  // (R,S)   = 4
#define NB  172  // (R,S)   = 4
#define H0W 176  // (S,G)   = 16
#define WTOT 192

__device__ __forceinline__ float f4get(const float4 v, int e) {
    return e == 0 ? v.x : e == 1 ? v.y : e == 2 ? v.z : v.w;
}

__device__ __forceinline__ float fast_tanh(float x) {
    float e2 = __expf(2.0f * x);
    return 1.0f - 2.0f / (e2 + 1.0f);
}

// Full-wave (64-lane) sum via DPP — pure VALU, no LDS pipe. Result valid in lane 63.
#define DPP_ADD_F(x, ctrl) \
    x += __int_as_float(__builtin_amdgcn_update_dpp(0, __float_as_int(x), (ctrl), 0xf, 0xf, true))

__device__ __forceinline__ float wave_reduce63(float x) {
    DPP_ADD_F(x, 0x111);  // row_shr:1
    DPP_ADD_F(x, 0x112);  // row_shr:2
    DPP_ADD_F(x, 0x114);  // row_shr:4
    DPP_ADD_F(x, 0x118);  // row_shr:8  -> lane 15 of each row has row sum
    DPP_ADD_F(x, 0x142);  // row_bcast:15 -> lane 31 has lanes 0-31, lane 63 has 32-63
    DPP_ADD_F(x, 0x143);  // row_bcast:31 -> lane 63 has full sum
    return x;
}

__global__ __launch_bounds__(NTHREADS, 1) void rnn_kernel(
    const float* __restrict__ input,   // (B,T,I)
    const float* __restrict__ noise,   // (B,T,H)
    const float* __restrict__ gb,      // (G,H)
    const float* __restrict__ sup,     // (S,H)
    const float* __restrict__ wi_w,    // (I,S,G)
    const float* __restrict__ m_w,     // (R,S,G)
    const float* __restrict__ n_w,     // (R,S,G)
    const float* __restrict__ wo_w,    // (O,S,G)
    const float* __restrict__ wi_b,    // (I,S)
    const float* __restrict__ m_b,     // (R,S)
    const float* __restrict__ n_b,     // (R,S)
    const float* __restrict__ h0_w,    // (S,G)
    float* __restrict__ out)           // (B,T,O) then (B,T,H), flat
{
    const int b    = blockIdx.x;
    const int tid  = threadIdx.x;
    const int wave = tid >> 6;
    const int lane = tid & 63;

    __shared__ float  s_input[T_DIM * I_DIM];  // 16 KB
    __shared__ float2 s_out[T_DIM];            // 8 KB
    __shared__ float4 s_part[2][NWAVES];       // double-buffered wave partials
    __shared__ float  s_w[WTOT];

    // ---- stage input[b] and small weights into LDS ----
    {
        const float4* inp4 = (const float4*)(input + (size_t)b * (T_DIM * I_DIM));
        float4* sIn4 = (float4*)s_input;
        #pragma unroll
        for (int k = tid; k < T_DIM * I_DIM / 4; k += NTHREADS) sIn4[k] = inp4[k];

        if (tid < 64)       s_w[tid] = wi_w[tid];
        else if (tid < 96)  s_w[tid] = m_w[tid - 64];
        else if (tid < 128) s_w[tid] = n_w[tid - 96];
        else if (tid < 160) s_w[tid] = wo_w[tid - 128];
        else if (tid < 168) s_w[tid] = wi_b[tid - 160];
        else if (tid < 172) s_w[tid] = m_b[tid - 168];
        else if (tid < 176) s_w[tid] = n_b[tid - 172];
        else if (tid < 192) s_w[tid] = h0_w[tid - 176];
    }
    __syncthreads();

    // Each thread owns two contiguous float4 chunks of H:
    //   chunk 0: floats [4*tid .. 4*tid+3]        (block covers 0..1023)
    //   chunk 1: floats [1024+4*tid .. +3]        (block covers 1024..2047)
    // => every global load/store instruction is perfectly contiguous.
    const int h_off0 = 4 * tid;
    const int h_off1 = 1024 + 4 * tid;

    float wiP[EPT][I_DIM], mP[EPT][R_DIM], nP[EPT][R_DIM], woP[EPT][O_DIM];
    float h_reg[EPT], g_reg[EPT];

    #pragma unroll
    for (int c = 0; c < 2; ++c) {
        const int hb = c == 0 ? h_off0 : h_off1;
        float4 gbv[G_DIM];
        #pragma unroll
        for (int g = 0; g < G_DIM; ++g)
            gbv[g] = *(const float4*)(gb + (size_t)g * H_DIM + hb);
        float4 supv[S_DIM];
        #pragma unroll
        for (int s = 0; s < S_DIM; ++s)
            supv[s] = *(const float4*)(sup + (size_t)s * H_DIM + hb);

        #pragma unroll
        for (int j = 0; j < 4; ++j) {
            const int e = c * 4 + j;
            float gcol[G_DIM];
            #pragma unroll
            for (int g = 0; g < G_DIM; ++g) gcol[g] = f4get(gbv[g], j);

            #pragma unroll
            for (int i = 0; i < I_DIM; ++i) wiP[e][i] = 0.0f;
            #pragma unroll
            for (int r = 0; r < R_DIM; ++r) { mP[e][r] = 0.0f; nP[e][r] = 0.0f; }
            #pragma unroll
            for (int o = 0; o < O_DIM; ++o) woP[e][o] = 0.0f;
            float h0v = 0.0f;

            #pragma unroll
            for (int s = 0; s < S_DIM; ++s) {
                float sv = f4get(supv[s], j);
                #pragma unroll
                for (int i = 0; i < I_DIM; ++i) {
                    float d = 0.0f;
                    #pragma unroll
                    for (int g = 0; g < G_DIM; ++g)
                        d = fmaf(s_w[WIW + (i * S_DIM + s) * G_DIM + g], gcol[g], d);
                    wiP[e][i] = fmaf(sv, d + s_w[WIB + i * S_DIM + s], wiP[e][i]);
                }
                #pragma unroll
                for (int r = 0; r < R_DIM; ++r) {
                    float dm = 0.0f, dn = 0.0f;
                    #pragma unroll
                    for (int g = 0; g < G_DIM; ++g) {
                        dm = fmaf(s_w[MW + (r * S_DIM + s) * G_DIM + g], gcol[g], dm);
                        dn = fmaf(s_w[NW + (r * S_DIM + s) * G_DIM + g], gcol[g], dn);
                    }
                    mP[e][r] = fmaf(sv, dm + s_w[MB + r * S_DIM + s], mP[e][r]);
                    nP[e][r] = fmaf(sv, dn + s_w[NB + r * S_DIM + s], nP[e][r]);
                }
                #pragma unroll
                for (int o = 0; o < O_DIM; ++o) {
                    float d = 0.0f;
                    #pragma unroll
                    for (int g = 0; g < G_DIM; ++g)
                        d = fmaf(s_w[WOW + (o * S_DIM + s) * G_DIM + g], gcol[g], d);
                    woP[e][o] = fmaf(sv, d, woP[e][o]);
                }
                {
                    float d = 0.0f;
                    #pragma unroll
                    for (int g = 0; g < G_DIM; ++g)
                        d = fmaf(s_w[H0W + s * G_DIM + g], gcol[g], d);
                    h0v = fmaf(sv, d, h0v);
                }
            }
            h_reg[e] = h0v;
            g_reg[e] = fast_tanh(h0v);
        }
    }

    // ---- noise prefetch ring (modulo-indexed; loop unrolled x4 below) ----
    const float4* noi4 = (const float4*)(noise + (size_t)b * T_DIM * H_DIM);
    float4* traj4 = (float4*)(out + (size_t)B_DIM * T_DIM * O_DIM + (size_t)b * T_DIM * H_DIM);
    const int f4_0 = tid;        // chunk-0 float4 index within a step's 512
    const int f4_1 = 256 + tid;  // chunk-1

    float4 ring[PF_DEPTH][2];
    #pragma unroll
    for (int d = 0; d < PF_DEPTH; ++d) {
        ring[d][0] = noi4[(size_t)d * 512 + f4_0];
        ring[d][1] = noi4[(size_t)d * 512 + f4_1];
    }

    // ---- main scan ----
    #pragma unroll 4
    for (int t = 0; t < T_DIM; ++t) {
        const int buf = t & 1;
        const int slot = t & (PF_DEPTH - 1);

        // partials: kappa (g.n) and out_t (g.wo) from the same g
        float p0 = 0.f, p1 = 0.f, p2 = 0.f, p3 = 0.f;
        #pragma unroll
        for (int e = 0; e < EPT; ++e) {
            float g = g_reg[e];
            p0 = fmaf(g, nP[e][0], p0);
            p1 = fmaf(g, nP[e][1], p1);
            p2 = fmaf(g, woP[e][0], p2);
            p3 = fmaf(g, woP[e][1], p3);
        }
        p0 = wave_reduce63(p0);
        p1 = wave_reduce63(p1);
        p2 = wave_reduce63(p2);
        p3 = wave_reduce63(p3);
        if (lane == 63) s_part[buf][wave] = make_float4(p0, p1, p2, p3);
        __syncthreads();

        float4 tot = s_part[buf][0];
        #pragma unroll
        for (int w = 1; w < NWAVES; ++w) {
            float4 q = s_part[buf][w];
            tot.x += q.x; tot.y += q.y; tot.z += q.z; tot.w += q.w;
        }
        if (t > 0 && tid == 0)
            s_out[t - 1] = make_float2(tot.z * INV_H, tot.w * INV_H);

        const float k0 = tot.x * INV_H;
        const float k1 = tot.y * INV_H;

        // consume ring slot, refill with t+PF_DEPTH
        float4 nz0 = ring[slot][0];
        float4 nz1 = ring[slot][1];
        {
            int tp = t + PF_DEPTH; if (tp > T_DIM - 1) tp = T_DIM - 1;
            ring[slot][0] = noi4[(size_t)tp * 512 + f4_0];
            ring[slot][1] = noi4[(size_t)tp * 512 + f4_1];
        }

        const float4 uin = *(const float4*)(s_input + t * I_DIM);

        float4 tr0, tr1;
        #pragma unroll
        for (int e = 0; e < EPT; ++e) {
            float u = uin.x * wiP[e][0];
            u = fmaf(uin.y, wiP[e][1], u);
            u = fmaf(uin.z, wiP[e][2], u);
            u = fmaf(uin.w, wiP[e][3], u);
            float rec = k0 * mP[e][0];
            rec = fmaf(k1, mP[e][1], rec);
            float nzv = e < 4 ? f4get(nz0, e) : f4get(nz1, e - 4);
            float h = h_reg[e];
            h = h + NOISE_STD * nzv + ALPHA * (rec + u - h);
            h_reg[e] = h;
            g_reg[e] = fast_tanh(h);
            float* trp = e < 4 ? (float*)&tr0 : (float*)&tr1;
            trp[e & 3] = h;
        }
        traj4[(size_t)t * 512 + f4_0] = tr0;
        traj4[(size_t)t * 512 + f4_1] = tr1;
    }

    // ---- final out[T-1] reduction ----
    {
        float p2 = 0.f, p3 = 0.f;
        #pragma unroll
        for (int e = 0; e < EPT; ++e) {
            p2 = fmaf(g_reg[e], woP[e][0], p2);
            p3 = fmaf(g_reg[e], woP[e][1], p3);
        }
        p2 = wave_reduce63(p2);
        p3 = wave_reduce63(p3);
        if (lane == 63) s_part[0][wave] = make_float4(p2, p3, 0.f, 0.f);
        __syncthreads();
        if (tid == 0) {
            float a = 0.f, c = 0.f;
            #pragma unroll
            for (int w = 0; w < NWAVES; ++w) { a += s_part[0][w].x; c += s_part[0][w].y; }
            s_out[T_DIM - 1] = make_float2(a * INV_H, c * INV_H);
        }
        __syncthreads();
    }

    // ---- flush output (B,T,O) block for this b: 2048 floats, coalesced ----
    {
        float4* outg = (float4*)(out + (size_t)b * T_DIM * O_DIM);
        const float4* outl = (const float4*)s_out;
        outg[tid]       = outl[tid];
        outg[tid + 256] = outl[tid + 256];
    }
}

extern "C" void kernel_launch(void* const* d_in, const int* in_sizes, int n_in,
                              void* d_out, int out_size, void* d_ws, size_t ws_size,
                              hipStream_t stream) {
    rnn_kernel<<<B_DIM, NTHREADS, 0, stream>>>(
        (const float*)d_in[0],  // input
        (const float*)d_in[1],  // noise
        (const float*)d_in[2],  // gaussian_basis
        (const float*)d_in[3],  // supports
        (const float*)d_in[4],  // wi_weights
        (const float*)d_in[5],  // m_weights
        (const float*)d_in[6],  // n_weights
        (const float*)d_in[7],  // wo_weights
        (const float*)d_in[8],  // wi_biases
        (const float*)d_in[9],  // m_biases
        (const float*)d_in[10], // n_biases
        (const float*)d_in[11], // h0_weights
        (float*)d_out);
}